// Round 5
// baseline (735.091 us; speedup 1.0000x reference)
//
#include <hip/hip_runtime.h>
#include <math.h>

#define CHUNK 32
#define DK 128
#define DV 128
#define L_SEQ 4096
#define BH 32
#define NCH 128

typedef __attribute__((ext_vector_type(8))) short bf16x8;
typedef __attribute__((ext_vector_type(4))) float f32x4;

union U8 { unsigned int u[4]; bf16x8 v; };

#define MFMA16(a, b, c) __builtin_amdgcn_mfma_f32_16x16x32_bf16((a), (b), (c), 0, 0, 0)
#define LGKM_WAIT() __asm__ __volatile__("s_waitcnt lgkmcnt(0)" ::: "memory")

__device__ __forceinline__ unsigned short f2bf(float x){
    unsigned int u = __builtin_bit_cast(unsigned int, x);
    u = u + 0x7FFFu + ((u >> 16) & 1u);   // RNE
    return (unsigned short)(u >> 16);
}
__device__ __forceinline__ unsigned int pk2(float a, float b){
    return (unsigned int)f2bf(a) | ((unsigned int)f2bf(b) << 16);
}

__device__ __forceinline__ bf16x8 afragF32(const float (*M)[36], int row, int q8){
    float4 f0 = *(const float4*)&M[row][q8];
    float4 f1 = *(const float4*)&M[row][q8 + 4];
    U8 t;
    t.u[0] = pk2(f0.x, f0.y); t.u[1] = pk2(f0.z, f0.w);
    t.u[2] = pk2(f1.x, f1.y); t.u[3] = pk2(f1.z, f1.w);
    return t.v;
}
__device__ __forceinline__ bf16x8 bfragF32(const float (*M)[36], int q8, int col){
    U8 t;
#pragma unroll
    for (int j2 = 0; j2 < 4; ++j2)
        t.u[j2] = pk2(M[q8 + 2*j2][col], M[q8 + 2*j2 + 1][col]);
    return t.v;
}

// ---------------- Phase 1: per-chunk prep, frag-direct loads, MFMA ---------
// One 64-thread block per (bh,chunk). Outputs (all bf16):
//   qw/kw : L2-normalized q/k rows [bh][L][128]
//   kwT   : kn transposed [bh][128][L]   (for scan's S-update A-frags)
//   Tw    : T=(I+A)^{-1}  [bh][nch][32][32];  Aw : tril(qn kn^T)

__global__ __launch_bounds__(64, 1)
void prep_kernel(const float* __restrict__ q, const float* __restrict__ k,
                 const float* __restrict__ beta,
                 unsigned short* __restrict__ qw, unsigned short* __restrict__ kw,
                 unsigned short* __restrict__ kwT,
                 unsigned short* __restrict__ Tw, unsigned short* __restrict__ Aw)
{
    const int bc = blockIdx.x;               // bh*NCH + ch
    const int bh = bc >> 7, ch = bc & 127;
    const size_t row0 = (size_t)bc * CHUNK;
    const int l = threadIdx.x;
    const int quad = l >> 4, ln15 = l & 15, q8 = quad * 8;

    __shared__ float Ms[32][36];
    __shared__ float Rs[32][36];

    float betr[2];
#pragma unroll
    for (int mt = 0; mt < 2; ++mt) betr[mt] = beta[row0 + 16*mt + ln15];

    bf16x8 qnf[2][4], knf[2][4], kbf[2][4];
    unsigned short ke[2][4][8];

#pragma unroll
    for (int mt = 0; mt < 2; ++mt){
        // ---- q row: frag-layout load, row sumsq via cross-quad shuffles ----
        {
            const float* qp = q + (row0 + 16*mt + ln15) * DK + q8;
            float buf[32]; float s = 0.f;
#pragma unroll
            for (int ks = 0; ks < 4; ++ks){
                float4 a = *(const float4*)(qp + 32*ks);
                float4 b = *(const float4*)(qp + 32*ks + 4);
                buf[8*ks+0]=a.x; buf[8*ks+1]=a.y; buf[8*ks+2]=a.z; buf[8*ks+3]=a.w;
                buf[8*ks+4]=b.x; buf[8*ks+5]=b.y; buf[8*ks+6]=b.z; buf[8*ks+7]=b.w;
                s += a.x*a.x+a.y*a.y+a.z*a.z+a.w*a.w
                   + b.x*b.x+b.y*b.y+b.z*b.z+b.w*b.w;
            }
            s += __shfl_xor(s, 16);
            s += __shfl_xor(s, 32);
            float sc = rsqrtf(s + 1e-6f);
#pragma unroll
            for (int ks = 0; ks < 4; ++ks){
                U8 t;
#pragma unroll
                for (int j2 = 0; j2 < 4; ++j2)
                    t.u[j2] = pk2(buf[8*ks+2*j2]*sc, buf[8*ks+2*j2+1]*sc);
                qnf[mt][ks] = t.v;
                *(bf16x8*)(qw + (row0 + 16*mt + ln15)*DK + 32*ks + q8) = t.v;
            }
        }
        // ---- k row: kn + kb = kn*beta ----
        {
            const float* kp = k + (row0 + 16*mt + ln15) * DK + q8;
            float buf[32]; float s = 0.f;
#pragma unroll
            for (int ks = 0; ks < 4; ++ks){
                float4 a = *(const float4*)(kp + 32*ks);
                float4 b = *(const float4*)(kp + 32*ks + 4);
                buf[8*ks+0]=a.x; buf[8*ks+1]=a.y; buf[8*ks+2]=a.z; buf[8*ks+3]=a.w;
                buf[8*ks+4]=b.x; buf[8*ks+5]=b.y; buf[8*ks+6]=b.z; buf[8*ks+7]=b.w;
                s += a.x*a.x+a.y*a.y+a.z*a.z+a.w*a.w
                   + b.x*b.x+b.y*b.y+b.z*b.z+b.w*b.w;
            }
            s += __shfl_xor(s, 16);
            s += __shfl_xor(s, 32);
            float sc = rsqrtf(s + 1e-6f);
            float bb = betr[mt];
#pragma unroll
            for (int ks = 0; ks < 4; ++ks){
                U8 t, tb;
#pragma unroll
                for (int j2 = 0; j2 < 4; ++j2){
                    float x0 = buf[8*ks+2*j2]*sc, x1 = buf[8*ks+2*j2+1]*sc;
                    unsigned short e0 = f2bf(x0), e1 = f2bf(x1);
                    ke[mt][ks][2*j2] = e0; ke[mt][ks][2*j2+1] = e1;
                    t.u[j2]  = (unsigned)e0 | ((unsigned)e1 << 16);
                    tb.u[j2] = pk2(x0*bb, x1*bb);
                }
                knf[mt][ks] = t.v; kbf[mt][ks] = tb.v;
                *(bf16x8*)(kw + (row0 + 16*mt + ln15)*DK + 32*ks + q8) = t.v;
            }
        }
    }

    // ---- kwT scalar stores (off any critical path) ----
#pragma unroll
    for (int mt = 0; mt < 2; ++mt)
#pragma unroll
    for (int ks = 0; ks < 4; ++ks)
#pragma unroll
    for (int j = 0; j < 8; ++j)
        kwT[((size_t)bh*DK + 32*ks + q8 + j)*L_SEQ + ch*CHUNK + 16*mt + ln15] = ke[mt][ks][j];

    // ---- B = kb @ kn^T ; attn = qn @ kn^T (B-operand frag == kn A-frag data) ----
    f32x4 Z = {0.f, 0.f, 0.f, 0.f};
    f32x4 Bacc[2][2] = {{Z, Z}, {Z, Z}};
    f32x4 Aacc[2][2] = {{Z, Z}, {Z, Z}};
#pragma unroll
    for (int ks = 0; ks < 4; ++ks)
#pragma unroll
    for (int mt = 0; mt < 2; ++mt)
#pragma unroll
    for (int nt = 0; nt < 2; ++nt){
        Bacc[mt][nt] = MFMA16(kbf[mt][ks], knf[nt][ks], Bacc[mt][nt]);
        Aacc[mt][nt] = MFMA16(qnf[mt][ks], knf[nt][ks], Aacc[mt][nt]);
    }

    // ---- masks; store attn; stage B; init R = I + B ----
    f32x4 Rc[2][2];
#pragma unroll
    for (int mt = 0; mt < 2; ++mt)
#pragma unroll
    for (int nt = 0; nt < 2; ++nt)
#pragma unroll
    for (int rg = 0; rg < 4; ++rg){
        int row = 16*mt + 4*quad + rg, col = 16*nt + ln15;
        float av = (col <= row) ? Aacc[mt][nt][rg] : 0.f;
        Aw[((size_t)bc << 10) + row*32 + col] = f2bf(av);
        float bm = (col < row) ? -Bacc[mt][nt][rg] : 0.f;
        Ms[row][col] = bm;
        Rc[mt][nt][rg] = bm + ((col == row) ? 1.f : 0.f);
    }

    // ---- doubling: R <- R(I+B^2)(I+B^4)(I+B^8)(I+B^16) ----
#pragma unroll 1
    for (int rd = 0; rd < 4; ++rd){
        LGKM_WAIT();
        bf16x8 Am[2], Bm2[2];
#pragma unroll
        for (int mt = 0; mt < 2; ++mt) Am[mt] = afragF32(Ms, 16*mt + ln15, q8);
#pragma unroll
        for (int nt = 0; nt < 2; ++nt) Bm2[nt] = bfragF32(Ms, q8, 16*nt + ln15);
        f32x4 Mq[2][2];
#pragma unroll
        for (int mt = 0; mt < 2; ++mt)
#pragma unroll
        for (int nt = 0; nt < 2; ++nt)
            Mq[mt][nt] = MFMA16(Am[mt], Bm2[nt], Z);
#pragma unroll
        for (int mt = 0; mt < 2; ++mt)
#pragma unroll
        for (int nt = 0; nt < 2; ++nt)
#pragma unroll
        for (int rg = 0; rg < 4; ++rg){
            int row = 16*mt + 4*quad + rg, col = 16*nt + ln15;
            Rs[row][col] = Rc[mt][nt][rg];
            Ms[row][col] = Mq[mt][nt][rg];
        }
        LGKM_WAIT();
        bf16x8 Ar[2], Bq[2];
#pragma unroll
        for (int mt = 0; mt < 2; ++mt) Ar[mt] = afragF32(Rs, 16*mt + ln15, q8);
#pragma unroll
        for (int nt = 0; nt < 2; ++nt) Bq[nt] = bfragF32(Ms, q8, 16*nt + ln15);
#pragma unroll
        for (int mt = 0; mt < 2; ++mt)
#pragma unroll
        for (int nt = 0; nt < 2; ++nt)
            Rc[mt][nt] = MFMA16(Ar[mt], Bq[nt], Rc[mt][nt]);   // R += R~ * M^2
    }

    // ---- store T ----
#pragma unroll
    for (int mt = 0; mt < 2; ++mt)
#pragma unroll
    for (int nt = 0; nt < 2; ++nt)
#pragma unroll
    for (int rg = 0; rg < 4; ++rg){
        int row = 16*mt + 4*quad + rg, col = 16*nt + ln15;
        Tw[((size_t)bc << 10) + row*32 + col] = f2bf(Rc[mt][nt][rg]);
    }
}

// ---------------- Phase 2: sequential scan — zero LDS, zero barriers -------
// grid 256: id = bh + 32*cb. S master (d x c) in fp32 C-frags; all frag-layout
// conversions via quad-swap ds_bpermute; kn^T A-frags loaded from kwT.

__global__ __launch_bounds__(64, 1)
void scan_kernel(const float* __restrict__ v, const float* __restrict__ beta,
                 const unsigned short* __restrict__ qw, const unsigned short* __restrict__ kw,
                 const unsigned short* __restrict__ kwT,
                 const unsigned short* __restrict__ Tw, const unsigned short* __restrict__ Aw,
                 float* __restrict__ out)
{
    const int id = blockIdx.x;
    const int bh = id & 31, cb = id >> 5, c0 = cb * 16;
    const int l = threadIdx.x;
    const int quad = l >> 4, ln15 = l & 15, q8 = quad * 8;
    const int hi = l >> 5;

    const f32x4 Z = {0.f, 0.f, 0.f, 0.f};
    f32x4 Sacc[8];
#pragma unroll
    for (int t = 0; t < 8; ++t) Sacc[t] = Z;

    const size_t bhL = (size_t)bh * L_SEQ;
    const int a0 = (((l & 16) << 1) | ln15) << 2;   // lane 32*(quad&1)+ln15
    const int a1 = a0 + 64;                          // +16 lanes

    bf16x8 kAa[2][4], kAb[2][4];
    float vva[8], vvb[8], bta[8], btb[8];

    auto loadK = [&](int ch, bf16x8 (&kA)[2][4]){
        const unsigned short* kp = kw + (bhL + (size_t)ch * CHUNK) * DK;
#pragma unroll
        for (int mt = 0; mt < 2; ++mt)
#pragma unroll
        for (int ks = 0; ks < 4; ++ks)
            kA[mt][ks] = *(const bf16x8*)(kp + (16*mt + ln15) * DK + 32*ks + q8);
    };
    auto loadVB = [&](int ch, float (&vv)[8], float (&bt)[8]){
        const size_t row0 = bhL + (size_t)ch * CHUNK;
#pragma unroll
        for (int g = 0; g < 8; ++g){
            int i = 16*(g >> 2) + 4*quad + (g & 3);
            vv[g] = v[(row0 + i) * DV + c0 + ln15];
            bt[g] = beta[row0 + i];
        }
    };

    loadK(0, kAa);
    loadVB(0, vva, bta);

    auto body = [&](int ch, bf16x8 (&cur)[2][4], bf16x8 (&nxt)[2][4],
                    float (&vv)[8], float (&bt)[8],
                    float (&vvn)[8], float (&btn)[8]){
        const size_t row0 = bhL + (size_t)ch * CHUNK;

        // ---- issue current-chunk vmem early (L2-warm ws) ----
        bf16x8 qA[2][4];
        {
            const unsigned short* qp = qw + row0 * DK;
#pragma unroll
            for (int mt = 0; mt < 2; ++mt)
#pragma unroll
            for (int ks = 0; ks < 4; ++ks)
                qA[mt][ks] = *(const bf16x8*)(qp + (16*mt + ln15) * DK + 32*ks + q8);
        }
        bf16x8 kT[8];   // kn^T A-frags: [d=16t+ln15][i=q8..q8+7]
        {
            const unsigned short* tp = kwT + (size_t)bh * DK * L_SEQ
                                     + (size_t)ch * CHUNK + q8;
#pragma unroll
            for (int t = 0; t < 8; ++t)
                kT[t] = *(const bf16x8*)(tp + (size_t)(16*t + ln15) * L_SEQ);
        }
        bf16x8 tA[2], aA[2];
        {
            const unsigned short* Tp = Tw + ((size_t)(bh * NCH + ch) << 10);
            const unsigned short* Ap = Aw + ((size_t)(bh * NCH + ch) << 10);
#pragma unroll
            for (int mt = 0; mt < 2; ++mt){
                tA[mt] = *(const bf16x8*)(Tp + (16*mt + ln15) * 32 + q8);
                aA[mt] = *(const bf16x8*)(Ap + (16*mt + ln15) * 32 + q8);
            }
        }
        // ---- prefetch next chunk ----
        int chn = (ch + 1 < NCH) ? ch + 1 : NCH - 1;
        loadK(chn, nxt);
        loadVB(chn, vvn, btn);

        // ---- S C-frags -> B-frags via quad-swap bpermute ----
        int P[8][2];
#pragma unroll
        for (int t = 0; t < 8; ++t){
            P[t][0] = (int)pk2(Sacc[t][0], Sacc[t][1]);
            P[t][1] = (int)pk2(Sacc[t][2], Sacc[t][3]);
        }
        bf16x8 SB[4];
#pragma unroll
        for (int ks = 0; ks < 4; ++ks){
            U8 sb;
            int e, f;
            e = __builtin_amdgcn_ds_bpermute(a0, P[2*ks][0]);
            f = __builtin_amdgcn_ds_bpermute(a0, P[2*ks+1][0]);
            sb.u[0] = (unsigned)(hi ? f : e);
            e = __builtin_amdgcn_ds_bpermute(a0, P[2*ks][1]);
            f = __builtin_amdgcn_ds_bpermute(a0, P[2*ks+1][1]);
            sb.u[1] = (unsigned)(hi ? f : e);
            e = __builtin_amdgcn_ds_bpermute(a1, P[2*ks][0]);
            f = __builtin_amdgcn_ds_bpermute(a1, P[2*ks+1][0]);
            sb.u[2] = (unsigned)(hi ? f : e);
            e = __builtin_amdgcn_ds_bpermute(a1, P[2*ks][1]);
            f = __builtin_amdgcn_ds_bpermute(a1, P[2*ks+1][1]);
            sb.u[3] = (unsigned)(hi ? f : e);
            SB[ks] = sb.v;
        }

        // ---- Y = kn @ S  (split chains: 2 deep + add) ----
        f32x4 Ya[2], Yb[2];
#pragma unroll
        for (int mt = 0; mt < 2; ++mt){
            Ya[mt] = MFMA16(cur[mt][0], SB[0], Z);
            Yb[mt] = MFMA16(cur[mt][2], SB[2], Z);
        }
#pragma unroll
        for (int mt = 0; mt < 2; ++mt){
            Ya[mt] = MFMA16(cur[mt][1], SB[1], Ya[mt]);
            Yb[mt] = MFMA16(cur[mt][3], SB[3], Yb[mt]);
        }

        // ---- O partial = qn @ S (independent — fills Y->X latency) ----
        f32x4 O[2] = {Z, Z};
#pragma unroll
        for (int ks = 0; ks < 4; ++ks)
#pragma unroll
        for (int mt = 0; mt < 2; ++mt)
            O[mt] = MFMA16(qA[mt][ks], SB[ks], O[mt]);

        // ---- X = beta*(v - Y) -> B-frag via quad-swap bpermute ----
        unsigned PX[2][2];
#pragma unroll
        for (int mt = 0; mt < 2; ++mt){
            float x0 = bt[4*mt+0] * (vv[4*mt+0] - (Ya[mt][0] + Yb[mt][0]));
            float x1 = bt[4*mt+1] * (vv[4*mt+1] - (Ya[mt][1] + Yb[mt][1]));
            float x2 = bt[4*mt+2] * (vv[4*mt+2] - (Ya[mt][2] + Yb[mt][2]));
            float x3 = bt[4*mt+3] * (vv[4*mt+3] - (Ya[mt][3] + Yb[mt][3]));
            PX[mt][0] = pk2(x0, x1);
            PX[mt][1] = pk2(x2, x3);
        }
        U8 xb;
        {
            int e, f;
            e = __builtin_amdgcn_ds_bpermute(a0, (int)PX[0][0]);
            f = __builtin_amdgcn_ds_bpermute(a0, (int)PX[1][0]);
            xb.u[0] = (unsigned)(hi ? f : e);
            e = __builtin_amdgcn_ds_bpermute(a0, (int)PX[0][1]);
            f = __builtin_amdgcn_ds_bpermute(a0, (int)PX[1][1]);
            xb.u[1] = (unsigned)(hi ? f : e);
            e = __builtin_amdgcn_ds_bpermute(a1, (int)PX[0][0]);
            f = __builtin_amdgcn_ds_bpermute(a1, (int)PX[1][0]);
            xb.u[2] = (unsigned)(hi ? f : e);
            e = __builtin_amdgcn_ds_bpermute(a1, (int)PX[0][1]);
            f = __builtin_amdgcn_ds_bpermute(a1, (int)PX[1][1]);
            xb.u[3] = (unsigned)(hi ? f : e);
        }

        // ---- U = T @ X ----
        f32x4 Uf[2];
#pragma unroll
        for (int mt = 0; mt < 2; ++mt) Uf[mt] = MFMA16(tA[mt], xb.v, Z);
        unsigned PU[2][2];
#pragma unroll
        for (int mt = 0; mt < 2; ++mt){
            PU[mt][0] = pk2(Uf[mt][0], Uf[mt][1]);
            PU[mt][1] = pk2(Uf[mt][2], Uf[mt][3]);
        }
        U8 ub;
        {
            int e, f;
            e = __builtin_amdgcn_ds_bpermute(a0, (int)PU[0][0]);
            f = __builtin_amdgcn_ds_bpermute(a0, (int)PU[1][0]);
            ub.u[0] = (unsigned)(hi ? f : e);
            e = __builtin_amdgcn_ds_bpermute(a0, (int)PU[0][1]);
            f = __builtin_amdgcn_ds_bpermute(a0, (int)PU[1][1]);
            ub.u[1] = (unsigned)(hi ? f : e);
            e = __builtin_amdgcn_ds_bpermute(a1, (int)PU[0][0]);
            f = __builtin_amdgcn_ds_bpermute(a1, (int)PU[1][0]);
            ub.u[2] = (unsigned)(hi ? f : e);
            e = __builtin_amdgcn_ds_bpermute(a1, (int)PU[0][1]);
            f = __builtin_amdgcn_ds_bpermute(a1, (int)PU[1][1]);
            ub.u[3] = (unsigned)(hi ? f : e);
        }

        // ---- O += attn @ U ; store ----
#pragma unroll
        for (int mt = 0; mt < 2; ++mt) O[mt] = MFMA16(aA[mt], ub.v, O[mt]);
#pragma unroll
        for (int mt = 0; mt < 2; ++mt)
#pragma unroll
        for (int rg = 0; rg < 4; ++rg)
            out[(row0 + 16*mt + 4*quad + rg) * DV + c0 + ln15] = O[mt][rg];

        // ---- S += kn^T @ U (8 independent MFMAs) ----
#pragma unroll
        for (int t = 0; t < 8; ++t)
            Sacc[t] = MFMA16(kT[t], ub.v, Sacc[t]);
    };

    for (int ch = 0; ch < NCH; ch += 2){
        body(ch,     kAa, kAb, vva, bta, vvb, btb);
        body(ch + 1, kAb, kAa, vvb, btb, vva, bta);
    }
}

// ---------------- Fallback (round-1 fused kernel) if ws too small ----------

__global__ __launch_bounds__(512, 1)
void deltanet_fused(const float* __restrict__ q, const float* __restrict__ k,
                    const float* __restrict__ v, const float* __restrict__ beta,
                    float* __restrict__ out)
{
    const int bh = blockIdx.x;
    const int tid = threadIdx.x;
    const int n = L_SEQ / CHUNK;

    __shared__ float S[DK][DV + 1];
    __shared__ float qs[CHUNK][DK + 1];
    __shared__ float ks[CHUNK][DK + 1];
    __shared__ float vs[CHUNK][DV + 1];
    __shared__ float kbs[CHUNK][DK + 1];
    __shared__ float T[CHUNK][CHUNK + 1];
    __shared__ float at[CHUNK][CHUNK + 1];
    __shared__ float bet[CHUNK];

    for (int idx = tid; idx < DK * DV; idx += 512)
        S[idx / DV][idx % DV] = 0.f;
    __syncthreads();

    const size_t base_bh = (size_t)bh * L_SEQ;

    for (int ch = 0; ch < n; ++ch){
        const size_t row0 = base_bh + (size_t)ch * CHUNK;
        for (int idx = tid; idx < CHUNK * DK; idx += 512){
            int r = idx >> 7, c = idx & 127;
            size_t g = (row0 + (size_t)r) * DK + c;
            qs[r][c] = q[g]; ks[r][c] = k[g]; vs[r][c] = v[g];
        }
        if (tid < CHUNK) bet[tid] = beta[row0 + tid];
        __syncthreads();
        if (tid < 64){
            int r = tid & 31;
            const float* src = (tid < 32) ? &qs[r][0] : &ks[r][0];
            float s = 0.f;
            for (int d = 0; d < DK; ++d){ float x = src[d]; s += x * x; }
            at[(tid < 32) ? 0 : 1][r] = 1.0f / sqrtf(s + 1e-6f);
        }
        __syncthreads();
        for (int idx = tid; idx < CHUNK * DK; idx += 512){
            int r = idx >> 7, c = idx & 127;
            float qq = qs[r][c] * at[0][r];
            float kk = ks[r][c] * at[1][r];
            float b = bet[r];
            qs[r][c] = qq; ks[r][c] = kk; kbs[r][c] = kk * b; vs[r][c] *= b;
        }
        __syncthreads();
        for (int idx = tid; idx < CHUNK * CHUNK; idx += 512){
            int i = idx >> 5, j = idx & 31;
            float s = 0.f;
            if (j < i){
                for (int d = 0; d < DK; ++d) s += kbs[i][d] * ks[j][d];
                s = -s;
            }
            T[i][j] = s;
        }
        __syncthreads();
        for (int i = 1; i < CHUNK; ++i){
            float upd = 0.f;
            if (tid < i){
                int j = tid;
                for (int kk = j + 1; kk < i; ++kk) upd += T[i][kk] * T[kk][j];
            }
            __syncthreads();
            if (tid < i) T[i][tid] += upd;
            __syncthreads();
        }
        if (tid < CHUNK) T[tid][tid] = 1.0f;
        __syncthreads();
        {
            int c = tid & 127;
            int i0 = (tid >> 7) * 8;
            float uacc[8], wacc[8];
#pragma unroll
            for (int r = 0; r < 8; ++r){ uacc[r] = 0.f; wacc[r] = 0.f; }
            for (int j = 0; j < CHUNK; ++j){
                float vvv = vs[j][c], kb = kbs[j][c];
#pragma unroll
                for (int r = 0; r < 8; ++r){
                    float tt = T[i0 + r][j];
                    uacc[r] += tt * vvv; wacc[r] += tt * kb;
                }
            }
            __syncthreads();
#pragma unroll
            for (int r = 0; r < 8; ++r){ vs[i0 + r][c] = uacc[r]; kbs[i0 + r][c] = wacc[r]; }
        }
        __syncthreads();
        for (int idx = tid; idx < CHUNK * CHUNK; idx += 512){
            int i = idx >> 5, j = idx & 31;
            float s = 0.f;
            if (j <= i) for (int d = 0; d < DK; ++d) s += qs[i][d] * ks[j][d];
            at[i][j] = s;
        }
        __syncthreads();
        {
            int c = tid & 127;
            int i0 = (tid >> 7) * 8;
            float acc[8];
#pragma unroll
            for (int r = 0; r < 8; ++r) acc[r] = 0.f;
            for (int d = 0; d < DK; ++d){
                float sv = S[d][c];
#pragma unroll
                for (int r = 0; r < 8; ++r) acc[r] += kbs[i0 + r][d] * sv;
            }
#pragma unroll
            for (int r = 0; r < 8; ++r) vs[i0 + r][c] -= acc[r];
        }
        __syncthreads();
        {
            int c = tid & 127;
            int i0 = (tid >> 7) * 8;
            float acc[8];
#pragma unroll
            for (int r = 0; r < 8; ++r) acc[r] = 0.f;
            for (int d = 0; d < DK; ++d){
                float sv = S[d][c];
#pragma unroll
                for (int r = 0; r < 8; ++r) acc[r] += qs[i0 + r][d] * sv;
            }
            for (int j = 0; j < CHUNK; ++j){
                float uv = vs[j][c];
#pragma unroll
                for (int r = 0; r < 8; ++r) acc[r] += at[i0 + r][j] * uv;
            }
#pragma unroll
            for (int r = 0; r < 8; ++r)
                out[(row0 + (size_t)(i0 + r)) * DV + c] = acc[r];
        }
        __syncthreads();
        {
            int c = tid & 127;
            int d0 = (tid >> 7) * 32;
            float acc[32];
#pragma unroll
            for (int r = 0; r < 32; ++r) acc[r] = 0.f;
            for (int i = 0; i < CHUNK; ++i){
                float uv = vs[i][c];
#pragma unroll
                for (int r = 0; r < 32; ++r) acc[r] += ks[i][d0 + r] * uv;
            }
#pragma unroll
            for (int r = 0; r < 32; ++r) S[d0 + r][c] += acc[r];
        }
        __syncthreads();
    }
}

extern "C" void kernel_launch(void* const* d_in, const int* in_sizes, int n_in,
                              void* d_out, int out_size, void* d_ws, size_t ws_size,
                              hipStream_t stream) {
    const float* q = (const float*)d_in[0];
    const float* k = (const float*)d_in[1];
    const float* v = (const float*)d_in[2];
    const float* beta = (const float*)d_in[3];
    float* out = (float*)d_out;

    const size_t QK = (size_t)BH * L_SEQ * DK;       // 16,777,216
    const size_t TA = (size_t)BH * NCH * 1024;       //  4,194,304
    const size_t need = (3 * QK + 2 * TA) * sizeof(unsigned short); // ~117 MB

    if (ws_size >= need){
        unsigned short* qwp  = (unsigned short*)d_ws;
        unsigned short* kwp  = qwp + QK;
        unsigned short* kwTp = kwp + QK;
        unsigned short* Twp  = kwTp + QK;
        unsigned short* Awp  = Twp + TA;
        prep_kernel<<<BH * NCH, 64, 0, stream>>>(q, k, beta, qwp, kwp, kwTp, Twp, Awp);
        scan_kernel<<<BH * 8, 64, 0, stream>>>(v, beta, qwp, kwp, kwTp, Twp, Awp, out);
    } else {
        deltanet_fused<<<BH, 512, 0, stream>>>(q, k, v, beta, out);
    }
}